// Round 16
// baseline (115.769 us; speedup 1.0000x reference)
//
#include <hip/hip_runtime.h>
#include <limits.h>

#define NSIZES 6

// ============================ Geometry =====================================
#define FINE 8192
#define WPR 256
#define FINE_WORDS (FINE * WPR)
#define BYTEMAP_BYTES ((size_t)FINE * FINE)
#define STRIP 24
#define NSTRIPS 342                       // ceil(8192/24), last strip 8 rows

#define NSLICES 16
#define SLICE_SHIFT 9
#define NGROUPS 512                       // R5-fallback groups per slice

// R16 single-level band partition
#define NBLK 512                          // partition blocks
#define NBANDS 342                        // 24-row bands
#define CAPB 32                           // keys per (block,band); mean ~11.4

__device__ __constant__ int d_K[NSIZES] = {2, 3, 4, 6, 8, 12};

typedef float f4v __attribute__((ext_vector_type(4)));
typedef float f2v __attribute__((ext_vector_type(2)));

// =========================== shared helpers ================================
template<int K, int LIMIT>
__device__ __forceinline__ int count_straddle(unsigned int v, unsigned int vn, int B) {
    const unsigned long long win = ((unsigned long long)vn << 32) | (unsigned long long)v;
    int s0 = ((B + K - 1) / K) * K;
    const int send = min(B + 32, LIMIT);
    int c = 0;
    for (; s0 < send; s0 += K) {
        c += (((win >> (s0 - B)) & ((1ull << K) - 1ull)) != 0ull) ? 1 : 0;
    }
    return c;
}

__device__ __forceinline__ int fold2cnt(unsigned int x) {
    unsigned int t = x | (x >> 1);
    return __popc(t & 0x55555555u);
}
__device__ __forceinline__ int fold4cnt(unsigned int x) {
    unsigned int t = x | (x >> 1); t |= t >> 2;
    return __popc(t & 0x11111111u);
}
__device__ __forceinline__ int fold8cnt(unsigned int x) {
    unsigned int t = x | (x >> 1); t |= t >> 2; t |= t >> 4;
    return __popc(t & 0x01010101u);
}

// ============ Fast path (R16): LDS-fetch-add band partition ================
// 512 thr/block; TWO independent f4v NT loads per iteration (4 pts/thread,
// 2x MLP vs R15). Band = ux/24, rank via LDS atomicAdd. Also resets the
// count-kernel's ticket (graph-replay safe: part precedes count).
__global__ __launch_bounds__(512) void mpc16_part(
    const f4v* __restrict__ pts4,
    const float2* __restrict__ pts,
    const float* __restrict__ psz,
    const float* __restrict__ pcmin,
    unsigned int* __restrict__ buckets,       // [NBLK][NBANDS][CAPB]
    unsigned char* __restrict__ counts,       // [NBLK][NBANDS]
    int2* __restrict__ blockmm,
    int* __restrict__ ticket,
    int npts, int vpb)                        // vpb = f4v units per block (mult of 1024)
{
    __shared__ int lcnt[NBANDS];
    __shared__ int smin[8], smax[8];

    const float minx = pcmin[0];
    const float miny = pcmin[1];
    const float fine = psz[0] * 0.5f;   // 0.05f * 0.5 == 0.025f exactly

    const int tid = threadIdx.x;
    if (blockIdx.x == 0 && tid == 0) *ticket = 0;   // reset for fused finalize
    for (int t = tid; t < NBANDS; t += 512) lcnt[t] = 0;
    __syncthreads();

    unsigned int* bbase = buckets + (size_t)blockIdx.x * NBANDS * CAPB;
    const int j0 = blockIdx.x * vpb;
    const int nv = npts >> 1;

    int umin = INT_MAX, umax = INT_MIN;
    for (int it = 0; it * 1024 < vpb; ++it) {
        const int ja = j0 + it * 1024 + tid;
        const int jb = ja + 512;
        f4v qa, qb;
        const bool va = ja < nv;
        const bool vb = jb < nv;
        if (va) qa = __builtin_nontemporal_load(pts4 + ja);
        if (vb) qb = __builtin_nontemporal_load(pts4 + jb);   // 2nd load in flight

        if (va) {
            int ux0 = (int)floorf((qa.x - minx) / fine);
            int uy0 = (int)floorf((qa.y - miny) / fine);
            int ux1 = (int)floorf((qa.z - minx) / fine);
            int uy1 = (int)floorf((qa.w - miny) / fine);
            umin = min(umin, min(ux0, ux1));
            umax = max(umax, max(ux0, ux1));
            if ((unsigned)ux0 < FINE && (unsigned)uy0 < FINE) {
                const unsigned int key = ((unsigned)ux0 << 13) | (unsigned)uy0;
                const int rank = atomicAdd(&lcnt[ux0 / 24], 1);
                if (rank < CAPB) bbase[(ux0 / 24) * CAPB + rank] = key;
            }
            if ((unsigned)ux1 < FINE && (unsigned)uy1 < FINE) {
                const unsigned int key = ((unsigned)ux1 << 13) | (unsigned)uy1;
                const int rank = atomicAdd(&lcnt[ux1 / 24], 1);
                if (rank < CAPB) bbase[(ux1 / 24) * CAPB + rank] = key;
            }
        }
        if (vb) {
            int ux0 = (int)floorf((qb.x - minx) / fine);
            int uy0 = (int)floorf((qb.y - miny) / fine);
            int ux1 = (int)floorf((qb.z - minx) / fine);
            int uy1 = (int)floorf((qb.w - miny) / fine);
            umin = min(umin, min(ux0, ux1));
            umax = max(umax, max(ux0, ux1));
            if ((unsigned)ux0 < FINE && (unsigned)uy0 < FINE) {
                const unsigned int key = ((unsigned)ux0 << 13) | (unsigned)uy0;
                const int rank = atomicAdd(&lcnt[ux0 / 24], 1);
                if (rank < CAPB) bbase[(ux0 / 24) * CAPB + rank] = key;
            }
            if ((unsigned)ux1 < FINE && (unsigned)uy1 < FINE) {
                const unsigned int key = ((unsigned)ux1 << 13) | (unsigned)uy1;
                const int rank = atomicAdd(&lcnt[ux1 / 24], 1);
                if (rank < CAPB) bbase[(ux1 / 24) * CAPB + rank] = key;
            }
        }
    }
    // odd tail point (npts odd): block 0 thread 0
    if ((npts & 1) && blockIdx.x == 0 && tid == 0) {
        float2 p = pts[npts - 1];
        int ux = (int)floorf((p.x - minx) / fine);
        int uy = (int)floorf((p.y - miny) / fine);
        umin = min(umin, ux);
        umax = max(umax, ux);
        if ((unsigned)ux < FINE && (unsigned)uy < FINE) {
            const unsigned int key = ((unsigned)ux << 13) | (unsigned)uy;
            const int rank = atomicAdd(&lcnt[ux / 24], 1);
            if (rank < CAPB) bbase[(ux / 24) * CAPB + rank] = key;
        }
    }
    __syncthreads();

    for (int t = tid; t < NBANDS; t += 512)
        counts[(size_t)blockIdx.x * NBANDS + t] = (unsigned char)min(lcnt[t], CAPB);

    #pragma unroll
    for (int d = 32; d >= 1; d >>= 1) {
        umin = min(umin, __shfl_xor(umin, d));
        umax = max(umax, __shfl_xor(umax, d));
    }
    const int wv = tid >> 6;
    if ((tid & 63) == 0) { smin[wv] = umin; smax[wv] = umax; }
    __syncthreads();
    if (tid == 0) {
        int a = smin[0], b = smax[0];
        #pragma unroll
        for (int t = 1; t < 8; ++t) { a = min(a, smin[t]); b = max(b, smax[t]); }
        blockmm[blockIdx.x] = make_int2(a, b);    // plain store, no atomic
    }
}

// fused gather+dedupe+count+finalize: R14/R15-proven body; the LAST block
// (ticket pattern, fence-published plain stores) reduces partials+blockmm
// and writes the (3,6) output - saves one dispatch.
__global__ __launch_bounds__(1024) void mpc16_count(
    const unsigned int* __restrict__ buckets,
    const unsigned char* __restrict__ counts,
    int* __restrict__ partials,               // [NSTRIPS][6]
    const int2* __restrict__ blockmm,         // [NBLK]
    int* __restrict__ ticket,
    int* __restrict__ out)
{
    __shared__ unsigned int bits[STRIP * 256];   // 24 KiB bit tile
    __shared__ unsigned char cnts[NBLK];
    __shared__ unsigned int sh3[2][4][256];
    __shared__ unsigned int sh6[2][2][256];
    __shared__ unsigned int sh12[2][256];
    __shared__ unsigned int sh4x[256];
    __shared__ int scnt[NSIZES];
    __shared__ int isLast;

    const int g = blockIdx.x;                 // strip/band 0..341
    const int tid = threadIdx.x;
    const int lane = tid & 63;

    #pragma unroll
    for (int j = 0; j < 6; ++j) bits[j * 1024 + tid] = 0;
    if (tid < NSIZES) scnt[tid] = 0;
    if (tid < NBLK) cnts[tid] = counts[(size_t)tid * NBANDS + g];
    __syncthreads();

    const int r0 = g * STRIP;

    // 64 cells in flight: lane16 = tid&15 scans keys of cell cb
    const int lane16 = tid & 15;
    const int cell = tid >> 4;                // 0..63
    for (int cb = cell; cb < NBLK; cb += 64) {
        const int cnt = cnts[cb];
        const unsigned int* src = buckets + ((size_t)cb * NBANDS + g) * CAPB;
        for (int k = lane16; k < cnt; k += 16) {
            const unsigned int key = src[k];
            const int rl = (int)(key >> 13) - r0;          // 0..23
            const int col = key & 8191;
            atomicOr(&bits[rl * 256 + (col >> 5)], 1u << (col & 31));
        }
    }
    __syncthreads();

    // ---- proven count structure; barrier outside divergence ----
    int cs[NSIZES] = {0, 0, 0, 0, 0, 0};
    const int w = tid & 255;
    const int q = (tid >> 8) & 1;
    const int rq = r0 + q * 12;

    unsigned int e2[6], e3[4], e4[3], e6[2], e12 = 0;
    if (tid < 512) {
        unsigned int v[12];
        #pragma unroll
        for (int j = 0; j < 12; ++j) v[j] = bits[(q * 12 + j) * 256 + w];

        #pragma unroll
        for (int t = 0; t < 6; ++t) e2[t] = v[2*t] | v[2*t+1];
        #pragma unroll
        for (int t = 0; t < 4; ++t) e3[t] = v[3*t] | v[3*t+1] | v[3*t+2];
        #pragma unroll
        for (int t = 0; t < 3; ++t) e4[t] = e2[2*t] | e2[2*t+1];
        #pragma unroll
        for (int t = 0; t < 2; ++t) e6[t] = e3[2*t] | e3[2*t+1];
        e12 = e6[0] | e6[1];

        #pragma unroll
        for (int t = 0; t < 4; ++t) sh3[q][t][w] = e3[t];
        #pragma unroll
        for (int t = 0; t < 2; ++t) sh6[q][t][w] = e6[t];
        sh12[q][w] = e12;
        if (q == 1) sh4x[w] = e4[0];
    }
    __syncthreads();

    if (tid < 512) {
        const int B = 32 * w;
        #pragma unroll
        for (int t = 0; t < 6; ++t) cs[0] += fold2cnt(e2[t]);
        #pragma unroll
        for (int t = 0; t < 3; ++t) cs[2] += fold4cnt(e4[t]);
        if (q == 0) {
            cs[4] += fold8cnt(e4[0] | e4[1]);
            cs[4] += fold8cnt(e4[2] | sh4x[w]);
        } else {
            cs[4] += fold8cnt(e4[1] | e4[2]);
        }
        #pragma unroll
        for (int gg = 0; gg < 4; ++gg) {
            unsigned int vn = (w < 255) ? sh3[q][gg][w + 1] : 0u;
            cs[1] += count_straddle<3, 3 * 2731>(e3[gg], vn, B);
        }
        #pragma unroll
        for (int gg = 0; gg < 2; ++gg) {
            if (rq / 6 + gg < 1365) {   // x-clamp: rows 8190-8191 dropped for k=6
                unsigned int vn = (w < 255) ? sh6[q][gg][w + 1] : 0u;
                cs[3] += count_straddle<6, 6 * 1365>(e6[gg], vn, B);
            }
        }
        if (rq / 12 < 683) {
            unsigned int vn = (w < 255) ? sh12[q][w + 1] : 0u;
            cs[5] += count_straddle<12, 12 * 683>(e12, vn, B);
        }
    }

    #pragma unroll
    for (int sI = 0; sI < NSIZES; ++sI) {
        int x = cs[sI];
        #pragma unroll
        for (int d = 32; d >= 1; d >>= 1) x += __shfl_xor(x, d);
        if (lane == 0 && x != 0) atomicAdd(&scnt[sI], x);   // LDS only
    }
    __syncthreads();
    if (tid < NSIZES) partials[g * NSIZES + tid] = scnt[tid];  // plain store

    // ---- fused finalize: last block reduces everything ----
    __threadfence();                          // publish partials device-wide
    if (tid == 0) isLast = (atomicAdd(ticket, 1) == NSTRIPS - 1);
    __syncthreads();
    if (!isLast) return;

    __shared__ int sacc[16][NSIZES];
    __shared__ int smin[16], smax[16];
    __shared__ int fcnt[NSIZES];
    __shared__ int fmin, fmax;

    int c[NSIZES] = {0, 0, 0, 0, 0, 0};
    for (int i = tid; i < NSTRIPS; i += 1024) {
        #pragma unroll
        for (int s = 0; s < NSIZES; ++s) c[s] += partials[i * NSIZES + s];
    }
    int a = INT_MAX, b = INT_MIN;
    for (int i = tid; i < NBLK; i += 1024) {
        int2 mm = blockmm[i];
        a = min(a, mm.x);
        b = max(b, mm.y);
    }
    #pragma unroll
    for (int d = 32; d >= 1; d >>= 1) {
        #pragma unroll
        for (int s = 0; s < NSIZES; ++s) c[s] += __shfl_xor(c[s], d);
        a = min(a, __shfl_xor(a, d));
        b = max(b, __shfl_xor(b, d));
    }
    const int wv = tid >> 6;
    if (lane == 0) {
        #pragma unroll
        for (int s = 0; s < NSIZES; ++s) sacc[wv][s] = c[s];
        smin[wv] = a; smax[wv] = b;
    }
    __syncthreads();
    if (tid == 0) {
        int x = smin[0], y = smax[0];
        int f[NSIZES];
        #pragma unroll
        for (int s = 0; s < NSIZES; ++s) f[s] = sacc[0][s];
        #pragma unroll
        for (int t = 1; t < 16; ++t) {
            x = min(x, smin[t]); y = max(y, smax[t]);
            #pragma unroll
            for (int s = 0; s < NSIZES; ++s) f[s] += sacc[t][s];
        }
        fmin = x; fmax = y;
        #pragma unroll
        for (int s = 0; s < NSIZES; ++s) fcnt[s] = f[s];
    }
    __syncthreads();
    if (tid < NSIZES) {
        out[tid] = fcnt[tid];
        out[NSIZES + tid] = fmin / d_K[tid];       // umin >= 0
        out[2 * NSIZES + tid] = fmax / d_K[tid];   // includes OOB coords, as ref
    }
}

// ====================== Fallback shared kernels ============================
__global__ void mpc2_init(int* counters) {
    if (threadIdx.x == 0) { counters[6] = INT_MAX; counters[7] = INT_MIN; }
    if (threadIdx.x < NSIZES) counters[threadIdx.x] = 0;
}

__global__ void mpc2_finalize(const int* __restrict__ counters, int* __restrict__ out) {
    const int t = threadIdx.x;
    if (t < NSIZES) {
        out[t] = counters[t];
        out[NSIZES + t] = counters[6] / d_K[t];
        out[2 * NSIZES + t] = counters[7] / d_K[t];
    }
}

// Fallback B (R5): direct sliced bytemap scatter + bytemap count
__global__ __launch_bounds__(256) void mpc5_scatter(
    const f4v* __restrict__ pts4,
    const float2* __restrict__ pts,
    const float* __restrict__ psz,
    const float* __restrict__ pcmin,
    unsigned char* __restrict__ bm,
    int* __restrict__ counters,
    int npts)
{
    const float minx = pcmin[0];
    const float miny = pcmin[1];
    const float fine = psz[0] * 0.5f;

    const int bid = blockIdx.x;
    const unsigned int slice = (unsigned)((bid & 7) + ((bid >= NGROUPS * 8) ? 8 : 0));
    const int grp = (bid >> 3) & (NGROUPS - 1);
    const bool track = (slice == 0);

    const int nv = npts >> 1;
    const int cpg = (nv + NGROUPS - 1) / NGROUPS;
    const int i0 = grp * cpg;
    const int i1 = min(nv, i0 + cpg);

    int umin = INT_MAX, umax = INT_MIN;
    for (int i = i0 + (int)threadIdx.x; i < i1; i += 256) {
        f4v q = __builtin_nontemporal_load(pts4 + i);
        int ux0 = (int)floorf((q.x - minx) / fine);
        int uy0 = (int)floorf((q.y - miny) / fine);
        int ux1 = (int)floorf((q.z - minx) / fine);
        int uy1 = (int)floorf((q.w - miny) / fine);
        if (track) {
            umin = min(umin, min(ux0, ux1));
            umax = max(umax, max(ux0, ux1));
        }
        if (((unsigned)ux0 >> SLICE_SHIFT) == slice && (unsigned)uy0 < FINE)
            bm[(((size_t)(unsigned)ux0) << 13) + (unsigned)uy0] = 1;
        if (((unsigned)ux1 >> SLICE_SHIFT) == slice && (unsigned)uy1 < FINE)
            bm[(((size_t)(unsigned)ux1) << 13) + (unsigned)uy1] = 1;
    }
    if ((npts & 1) && grp == 0 && threadIdx.x == 0) {
        float2 p = pts[npts - 1];
        int ux = (int)floorf((p.x - minx) / fine);
        int uy = (int)floorf((p.y - miny) / fine);
        if (track) { umin = min(umin, ux); umax = max(umax, ux); }
        if (((unsigned)ux >> SLICE_SHIFT) == slice && (unsigned)uy < FINE)
            bm[(((size_t)(unsigned)ux) << 13) + (unsigned)uy] = 1;
    }
    if (track) {
        #pragma unroll
        for (int d = 32; d >= 1; d >>= 1) {
            umin = min(umin, __shfl_xor(umin, d));
            umax = max(umax, __shfl_xor(umax, d));
        }
        if ((threadIdx.x & 63) == 0) {
            atomicMin(&counters[6], umin);
            atomicMax(&counters[7], umax);
        }
    }
}

__global__ __launch_bounds__(512) void mpc4_count(
    const unsigned char* __restrict__ bm,
    int* __restrict__ counters)
{
    __shared__ unsigned int sh3[2][4][256];
    __shared__ unsigned int sh6[2][2][256];
    __shared__ unsigned int sh12[2][256];
    __shared__ unsigned int sh4x[256];
    __shared__ int scnt[NSIZES];

    const int w = threadIdx.x & 255;
    const int q = threadIdx.x >> 8;
    const int r0 = blockIdx.x * STRIP;
    const int rq = r0 + q * 12;

    if (threadIdx.x < NSIZES) scnt[threadIdx.x] = 0;

    unsigned int v[12];
    #pragma unroll
    for (int j = 0; j < 12; ++j) {
        unsigned int m = 0;
        const int row = rq + j;
        if (row < FINE) {
            const uint4* p = (const uint4*)(bm + (((size_t)row) << 13) + (w << 5));
            uint4 a = p[0], b = p[1];
            unsigned int ds[8] = {a.x, a.y, a.z, a.w, b.x, b.y, b.z, b.w};
            #pragma unroll
            for (int t = 0; t < 8; ++t) {
                unsigned int d = ds[t];
                d |= d >> 4; d |= d >> 2; d |= d >> 1;
                m |= (((d & 0x01010101u) * 0x01020408u) >> 24 & 0xFu) << (t * 4);
            }
        }
        v[j] = m;
    }

    unsigned int e2[6], e3[4], e4[3], e6[2], e12;
    #pragma unroll
    for (int t = 0; t < 6; ++t) e2[t] = v[2*t] | v[2*t+1];
    #pragma unroll
    for (int t = 0; t < 4; ++t) e3[t] = v[3*t] | v[3*t+1] | v[3*t+2];
    #pragma unroll
    for (int t = 0; t < 3; ++t) e4[t] = e2[2*t] | e2[2*t+1];
    #pragma unroll
    for (int t = 0; t < 2; ++t) e6[t] = e3[2*t] | e3[2*t+1];
    e12 = e6[0] | e6[1];

    #pragma unroll
    for (int t = 0; t < 4; ++t) sh3[q][t][w] = e3[t];
    #pragma unroll
    for (int t = 0; t < 2; ++t) sh6[q][t][w] = e6[t];
    sh12[q][w] = e12;
    if (q == 1) sh4x[w] = e4[0];
    __syncthreads();

    const int B = 32 * w;
    int c0 = 0, c1 = 0, c2 = 0, c3 = 0, c4 = 0, c5 = 0;

    #pragma unroll
    for (int t = 0; t < 6; ++t) c0 += fold2cnt(e2[t]);
    #pragma unroll
    for (int t = 0; t < 3; ++t) c2 += fold4cnt(e4[t]);
    if (q == 0) {
        c4 += fold8cnt(e4[0] | e4[1]);
        c4 += fold8cnt(e4[2] | sh4x[w]);
    } else {
        c4 += fold8cnt(e4[1] | e4[2]);
    }
    #pragma unroll
    for (int g = 0; g < 4; ++g) {
        unsigned int vn = (w < 255) ? sh3[q][g][w + 1] : 0u;
        c1 += count_straddle<3, 3 * 2731>(e3[g], vn, B);
    }
    #pragma unroll
    for (int g = 0; g < 2; ++g) {
        if (rq / 6 + g < 1365) {
            unsigned int vn = (w < 255) ? sh6[q][g][w + 1] : 0u;
            c3 += count_straddle<6, 6 * 1365>(e6[g], vn, B);
        }
    }
    if (rq / 12 < 683) {
        unsigned int vn = (w < 255) ? sh12[q][w + 1] : 0u;
        c5 += count_straddle<12, 12 * 683>(e12, vn, B);
    }

    int cs[NSIZES] = {c0, c1, c2, c3, c4, c5};
    #pragma unroll
    for (int s = 0; s < NSIZES; ++s) {
        int x = cs[s];
        #pragma unroll
        for (int d = 32; d >= 1; d >>= 1) x += __shfl_xor(x, d);
        if ((threadIdx.x & 63) == 0 && x != 0) atomicAdd(&scnt[s], x);
    }
    __syncthreads();
    if (threadIdx.x < NSIZES && scnt[threadIdx.x] != 0)
        atomicAdd(&counters[threadIdx.x], scnt[threadIdx.x]);
}

// Fallback C (R3): bitmap + atomics
__global__ __launch_bounds__(256) void mpc3_scatter(
    const float4* __restrict__ pts4,
    const float2* __restrict__ pts,
    const float* __restrict__ psz,
    const float* __restrict__ pcmin,
    unsigned int* __restrict__ bitmap,
    int* __restrict__ counters,
    int npts)
{
    const float minx = pcmin[0];
    const float miny = pcmin[1];
    const float fine = psz[0] * 0.5f;

    int umin = INT_MAX, umax = INT_MIN;
    const int nv = npts >> 1;
    const int stride = gridDim.x * blockDim.x;
    const int tid = blockIdx.x * blockDim.x + threadIdx.x;
    for (int i = tid; i < nv; i += stride) {
        float4 q = pts4[i];
        int ux0 = (int)floorf((q.x - minx) / fine);
        int uy0 = (int)floorf((q.y - miny) / fine);
        int ux1 = (int)floorf((q.z - minx) / fine);
        int uy1 = (int)floorf((q.w - miny) / fine);
        umin = min(umin, min(ux0, ux1));
        umax = max(umax, max(ux0, ux1));
        if ((unsigned)ux0 < FINE && (unsigned)uy0 < FINE)
            atomicOr(&bitmap[(unsigned)ux0 * WPR + ((unsigned)uy0 >> 5)], 1u << (uy0 & 31));
        if ((unsigned)ux1 < FINE && (unsigned)uy1 < FINE)
            atomicOr(&bitmap[(unsigned)ux1 * WPR + ((unsigned)uy1 >> 5)], 1u << (uy1 & 31));
    }
    if ((npts & 1) && tid == 0) {
        float2 p = pts[npts - 1];
        int ux = (int)floorf((p.x - minx) / fine);
        int uy = (int)floorf((p.y - miny) / fine);
        umin = min(umin, ux);
        umax = max(umax, ux);
        if ((unsigned)ux < FINE && (unsigned)uy < FINE)
            atomicOr(&bitmap[(unsigned)ux * WPR + ((unsigned)uy >> 5)], 1u << (uy & 31));
    }
    #pragma unroll
    for (int d = 32; d >= 1; d >>= 1) {
        umin = min(umin, __shfl_xor(umin, d));
        umax = max(umax, __shfl_xor(umax, d));
    }
    if ((threadIdx.x & 63) == 0) {
        atomicMin(&counters[6], umin);
        atomicMax(&counters[7], umax);
    }
}

__global__ __launch_bounds__(256) void mpc3_count(
    const unsigned int* __restrict__ bitmap,
    int* __restrict__ counters)
{
    __shared__ unsigned int sh[14][256];

    const int b = blockIdx.x;
    const int w = threadIdx.x;
    const int r0 = b * STRIP;
    const int nrows = min(STRIP, FINE - r0);

    unsigned int v[STRIP];
    #pragma unroll
    for (int j = 0; j < STRIP; ++j)
        v[j] = (j < nrows) ? bitmap[(size_t)(r0 + j) * WPR + w] : 0u;

    unsigned int g2[12], g3[8], g4[6], g6[4], g8[3], g12[2];
    #pragma unroll
    for (int j = 0; j < 12; ++j) g2[j] = v[2*j] | v[2*j+1];
    #pragma unroll
    for (int j = 0; j < 8;  ++j) g3[j] = v[3*j] | v[3*j+1] | v[3*j+2];
    #pragma unroll
    for (int j = 0; j < 6;  ++j) g4[j] = g2[2*j] | g2[2*j+1];
    #pragma unroll
    for (int j = 0; j < 4;  ++j) g6[j] = g3[2*j] | g3[2*j+1];
    #pragma unroll
    for (int j = 0; j < 3;  ++j) g8[j] = g4[2*j] | g4[2*j+1];
    #pragma unroll
    for (int j = 0; j < 2;  ++j) g12[j] = g6[2*j] | g6[2*j+1];

    #pragma unroll
    for (int j = 0; j < 8; ++j) sh[j][w] = g3[j];
    #pragma unroll
    for (int j = 0; j < 4; ++j) sh[8 + j][w] = g6[j];
    #pragma unroll
    for (int j = 0; j < 2; ++j) sh[12 + j][w] = g12[j];
    __syncthreads();

    int c0 = 0, c1 = 0, c2 = 0, c3 = 0, c4 = 0, c5 = 0;
    const int B = 32 * w;

    #pragma unroll
    for (int j = 0; j < 12; ++j) c0 += fold2cnt(g2[j]);
    #pragma unroll
    for (int j = 0; j < 6; ++j) c2 += fold4cnt(g4[j]);
    #pragma unroll
    for (int j = 0; j < 3; ++j) c4 += fold8cnt(g8[j]);
    #pragma unroll
    for (int j = 0; j < 8; ++j) {
        unsigned int vn = (w < 255) ? sh[j][w + 1] : 0u;
        c1 += count_straddle<3, 3 * 2731>(g3[j], vn, B);
    }
    #pragma unroll
    for (int j = 0; j < 4; ++j) {
        if (r0 / 6 + j < 1365) {
            unsigned int vn = (w < 255) ? sh[8 + j][w + 1] : 0u;
            c3 += count_straddle<6, 6 * 1365>(g6[j], vn, B);
        }
    }
    #pragma unroll
    for (int j = 0; j < 2; ++j) {
        unsigned int vn = (w < 255) ? sh[12 + j][w + 1] : 0u;
        c5 += count_straddle<12, 12 * 683>(g12[j], vn, B);
    }

    int cs[6] = {c0, c1, c2, c3, c4, c5};
    #pragma unroll
    for (int s = 0; s < 6; ++s) {
        int x = cs[s];
        #pragma unroll
        for (int d = 32; d >= 1; d >>= 1) x += __shfl_xor(x, d);
        if ((threadIdx.x & 63) == 0 && x != 0) atomicAdd(&counters[s], x);
    }
}

// ============================================================================
static inline size_t align256(size_t x) { return (x + 255) & ~(size_t)255; }

extern "C" void kernel_launch(void* const* d_in, const int* in_sizes, int n_in,
                              void* d_out, int out_size, void* d_ws, size_t ws_size,
                              hipStream_t stream) {
    const float2* pts  = (const float2*)d_in[0];
    const float* psz   = (const float*)d_in[1];
    const float* pcmin = (const float*)d_in[2];
    const int* gs      = (const int*)d_in[3];
    (void)gs;
    const int npts = in_sizes[0] / 2;

    // R16 layout: ~23 MB
    const size_t bk_b = align256((size_t)NBLK * NBANDS * CAPB * sizeof(unsigned int));
    const size_t ct_b = align256((size_t)NBLK * NBANDS);
    const size_t mm_b = align256((size_t)NBLK * sizeof(int2));
    const size_t pt_b = align256((size_t)NSTRIPS * NSIZES * sizeof(int));
    const size_t tk_b = 256;
    const size_t new_need = bk_b + ct_b + mm_b + pt_b + tk_b + 4096;

    const size_t byte_need = BYTEMAP_BYTES + 64;

    if (ws_size >= new_need) {
        char* p = (char*)d_ws;
        unsigned int* buckets = (unsigned int*)p;       p += bk_b;
        unsigned char* counts = (unsigned char*)p;      p += ct_b;
        int2* blockmm = (int2*)p;                       p += mm_b;
        int* partials = (int*)p;                        p += pt_b;
        int* ticket = (int*)p;

        const int nv = npts >> 1;
        int vpb = (nv + NBLK - 1) / NBLK;
        vpb = (vpb + 1023) & ~1023;
        if (vpb < 1024) vpb = 1024;

        mpc16_part<<<NBLK, 512, 0, stream>>>((const f4v*)pts, pts, psz, pcmin,
                                             buckets, counts, blockmm, ticket,
                                             npts, vpb);
        mpc16_count<<<NSTRIPS, 1024, 0, stream>>>(buckets, counts, partials,
                                                  blockmm, ticket, (int*)d_out);
    } else if (ws_size >= byte_need) {
        unsigned char* bm = (unsigned char*)d_ws;
        int* counters = (int*)((char*)d_ws + BYTEMAP_BYTES);

        hipMemsetAsync(d_ws, 0, BYTEMAP_BYTES, stream);
        mpc2_init<<<1, 64, 0, stream>>>(counters);
        mpc5_scatter<<<NGROUPS * NSLICES, 256, 0, stream>>>(
            (const f4v*)pts, pts, psz, pcmin, bm, counters, npts);
        mpc4_count<<<NSTRIPS, 512, 0, stream>>>(bm, counters);
        mpc2_finalize<<<1, 64, 0, stream>>>(counters, (int*)d_out);
    } else {
        unsigned int* bitmap = (unsigned int*)d_ws;
        int* counters = (int*)d_ws + FINE_WORDS;

        hipMemsetAsync(d_ws, 0, (size_t)FINE_WORDS * sizeof(unsigned int), stream);
        mpc2_init<<<1, 64, 0, stream>>>(counters);
        mpc3_scatter<<<2048, 256, 0, stream>>>((const float4*)pts, pts, psz, pcmin,
                                               bitmap, counters, npts);
        mpc3_count<<<NSTRIPS, 256, 0, stream>>>(bitmap, counters);
        mpc2_finalize<<<1, 64, 0, stream>>>(counters, (int*)d_out);
    }
}

// Round 17
// 39.669 us; speedup vs baseline: 2.9184x; 2.9184x over previous
//
#include <hip/hip_runtime.h>
#include <limits.h>

#define NSIZES 6

// ============================ Geometry =====================================
#define FINE 8192
#define WPR 256
#define FINE_WORDS (FINE * WPR)
#define BYTEMAP_BYTES ((size_t)FINE * FINE)
#define STRIP 24
#define NSTRIPS 342                       // ceil(8192/24), last strip 8 rows

#define NSLICES 16
#define SLICE_SHIFT 9
#define NGROUPS 512                       // R5-fallback groups per slice

// single-level band partition (R14/R15 proven geometry)
#define NBLK 512                          // partition blocks
#define NBANDS 342                        // 24-row bands
#define CAPB 32                           // keys per (block,band); mean ~11.4

__device__ __constant__ int d_K[NSIZES] = {2, 3, 4, 6, 8, 12};

typedef float f4v __attribute__((ext_vector_type(4)));
typedef float f2v __attribute__((ext_vector_type(2)));

// =========================== shared helpers ================================
template<int K, int LIMIT>
__device__ __forceinline__ int count_straddle(unsigned int v, unsigned int vn, int B) {
    const unsigned long long win = ((unsigned long long)vn << 32) | (unsigned long long)v;
    int s0 = ((B + K - 1) / K) * K;
    const int send = min(B + 32, LIMIT);
    int c = 0;
    for (; s0 < send; s0 += K) {
        c += (((win >> (s0 - B)) & ((1ull << K) - 1ull)) != 0ull) ? 1 : 0;
    }
    return c;
}

__device__ __forceinline__ int fold2cnt(unsigned int x) {
    unsigned int t = x | (x >> 1);
    return __popc(t & 0x55555555u);
}
__device__ __forceinline__ int fold4cnt(unsigned int x) {
    unsigned int t = x | (x >> 1); t |= t >> 2;
    return __popc(t & 0x11111111u);
}
__device__ __forceinline__ int fold8cnt(unsigned int x) {
    unsigned int t = x | (x >> 1); t |= t >> 2; t |= t >> 4;
    return __popc(t & 0x01010101u);
}

// ============ Fast path (R17): LDS-fetch-add band partition ================
// R15 structure + R16's 2x MLP (two independent f4v NT loads per iter).
// NO ticket/fence (R16 lesson: per-block __threadfence = L2 writeback per
// block on multi-XCD = 90us; the kernel-boundary release is free).
__global__ __launch_bounds__(512) void mpc17_part(
    const f4v* __restrict__ pts4,
    const float2* __restrict__ pts,
    const float* __restrict__ psz,
    const float* __restrict__ pcmin,
    unsigned int* __restrict__ buckets,       // [NBLK][NBANDS][CAPB]
    unsigned char* __restrict__ counts,       // [NBLK][NBANDS]
    int2* __restrict__ blockmm,
    int npts, int vpb)                        // vpb = f4v units per block (mult of 1024)
{
    __shared__ int lcnt[NBANDS];
    __shared__ int smin[8], smax[8];

    const float minx = pcmin[0];
    const float miny = pcmin[1];
    const float fine = psz[0] * 0.5f;   // 0.05f * 0.5 == 0.025f exactly

    const int tid = threadIdx.x;
    for (int t = tid; t < NBANDS; t += 512) lcnt[t] = 0;
    __syncthreads();

    unsigned int* bbase = buckets + (size_t)blockIdx.x * NBANDS * CAPB;
    const int j0 = blockIdx.x * vpb;
    const int nv = npts >> 1;

    int umin = INT_MAX, umax = INT_MIN;
    for (int it = 0; it * 1024 < vpb; ++it) {
        const int ja = j0 + it * 1024 + tid;
        const int jb = ja + 512;
        f4v qa, qb;
        const bool va = ja < nv;
        const bool vb = jb < nv;
        if (va) qa = __builtin_nontemporal_load(pts4 + ja);
        if (vb) qb = __builtin_nontemporal_load(pts4 + jb);   // 2nd load in flight

        if (va) {
            int ux0 = (int)floorf((qa.x - minx) / fine);
            int uy0 = (int)floorf((qa.y - miny) / fine);
            int ux1 = (int)floorf((qa.z - minx) / fine);
            int uy1 = (int)floorf((qa.w - miny) / fine);
            umin = min(umin, min(ux0, ux1));
            umax = max(umax, max(ux0, ux1));
            if ((unsigned)ux0 < FINE && (unsigned)uy0 < FINE) {
                const unsigned int key = ((unsigned)ux0 << 13) | (unsigned)uy0;
                const int rank = atomicAdd(&lcnt[ux0 / 24], 1);
                if (rank < CAPB) bbase[(ux0 / 24) * CAPB + rank] = key;
            }
            if ((unsigned)ux1 < FINE && (unsigned)uy1 < FINE) {
                const unsigned int key = ((unsigned)ux1 << 13) | (unsigned)uy1;
                const int rank = atomicAdd(&lcnt[ux1 / 24], 1);
                if (rank < CAPB) bbase[(ux1 / 24) * CAPB + rank] = key;
            }
        }
        if (vb) {
            int ux0 = (int)floorf((qb.x - minx) / fine);
            int uy0 = (int)floorf((qb.y - miny) / fine);
            int ux1 = (int)floorf((qb.z - minx) / fine);
            int uy1 = (int)floorf((qb.w - miny) / fine);
            umin = min(umin, min(ux0, ux1));
            umax = max(umax, max(ux0, ux1));
            if ((unsigned)ux0 < FINE && (unsigned)uy0 < FINE) {
                const unsigned int key = ((unsigned)ux0 << 13) | (unsigned)uy0;
                const int rank = atomicAdd(&lcnt[ux0 / 24], 1);
                if (rank < CAPB) bbase[(ux0 / 24) * CAPB + rank] = key;
            }
            if ((unsigned)ux1 < FINE && (unsigned)uy1 < FINE) {
                const unsigned int key = ((unsigned)ux1 << 13) | (unsigned)uy1;
                const int rank = atomicAdd(&lcnt[ux1 / 24], 1);
                if (rank < CAPB) bbase[(ux1 / 24) * CAPB + rank] = key;
            }
        }
    }
    // odd tail point (npts odd): block 0 thread 0
    if ((npts & 1) && blockIdx.x == 0 && tid == 0) {
        float2 p = pts[npts - 1];
        int ux = (int)floorf((p.x - minx) / fine);
        int uy = (int)floorf((p.y - miny) / fine);
        umin = min(umin, ux);
        umax = max(umax, ux);
        if ((unsigned)ux < FINE && (unsigned)uy < FINE) {
            const unsigned int key = ((unsigned)ux << 13) | (unsigned)uy;
            const int rank = atomicAdd(&lcnt[ux / 24], 1);
            if (rank < CAPB) bbase[(ux / 24) * CAPB + rank] = key;
        }
    }
    __syncthreads();

    for (int t = tid; t < NBANDS; t += 512)
        counts[(size_t)blockIdx.x * NBANDS + t] = (unsigned char)min(lcnt[t], CAPB);

    #pragma unroll
    for (int d = 32; d >= 1; d >>= 1) {
        umin = min(umin, __shfl_xor(umin, d));
        umax = max(umax, __shfl_xor(umax, d));
    }
    const int wv = tid >> 6;
    if ((tid & 63) == 0) { smin[wv] = umin; smax[wv] = umax; }
    __syncthreads();
    if (tid == 0) {
        int a = smin[0], b = smax[0];
        #pragma unroll
        for (int t = 1; t < 8; ++t) { a = min(a, smin[t]); b = max(b, smax[t]); }
        blockmm[blockIdx.x] = make_int2(a, b);    // plain store, no atomic
    }
}

// fused gather+dedupe+count (R14/R15-proven; no fence, no ticket).
__global__ __launch_bounds__(1024) void mpc14_count(
    const unsigned int* __restrict__ buckets,
    const unsigned char* __restrict__ counts,
    int* __restrict__ partials)               // [NSTRIPS][6]
{
    __shared__ unsigned int bits[STRIP * 256];   // 24 KiB bit tile
    __shared__ unsigned char cnts[NBLK];
    __shared__ unsigned int sh3[2][4][256];
    __shared__ unsigned int sh6[2][2][256];
    __shared__ unsigned int sh12[2][256];
    __shared__ unsigned int sh4x[256];
    __shared__ int scnt[NSIZES];

    const int g = blockIdx.x;                 // strip/band 0..341
    const int tid = threadIdx.x;
    const int lane = tid & 63;

    #pragma unroll
    for (int j = 0; j < 6; ++j) bits[j * 1024 + tid] = 0;
    if (tid < NSIZES) scnt[tid] = 0;
    if (tid < NBLK) cnts[tid] = counts[(size_t)tid * NBANDS + g];
    __syncthreads();

    const int r0 = g * STRIP;

    // 64 cells in flight: lane16 = tid&15 scans keys of cell cb
    const int lane16 = tid & 15;
    const int cell = tid >> 4;                // 0..63
    for (int cb = cell; cb < NBLK; cb += 64) {
        const int cnt = cnts[cb];
        const unsigned int* src = buckets + ((size_t)cb * NBANDS + g) * CAPB;
        for (int k = lane16; k < cnt; k += 16) {
            const unsigned int key = src[k];
            const int rl = (int)(key >> 13) - r0;          // 0..23
            const int col = key & 8191;
            atomicOr(&bits[rl * 256 + (col >> 5)], 1u << (col & 31));
        }
    }
    __syncthreads();

    // ---- proven count structure; barrier outside divergence ----
    int cs[NSIZES] = {0, 0, 0, 0, 0, 0};
    const int w = tid & 255;
    const int q = (tid >> 8) & 1;
    const int rq = r0 + q * 12;

    unsigned int e2[6], e3[4], e4[3], e6[2], e12 = 0;
    if (tid < 512) {
        unsigned int v[12];
        #pragma unroll
        for (int j = 0; j < 12; ++j) v[j] = bits[(q * 12 + j) * 256 + w];

        #pragma unroll
        for (int t = 0; t < 6; ++t) e2[t] = v[2*t] | v[2*t+1];
        #pragma unroll
        for (int t = 0; t < 4; ++t) e3[t] = v[3*t] | v[3*t+1] | v[3*t+2];
        #pragma unroll
        for (int t = 0; t < 3; ++t) e4[t] = e2[2*t] | e2[2*t+1];
        #pragma unroll
        for (int t = 0; t < 2; ++t) e6[t] = e3[2*t] | e3[2*t+1];
        e12 = e6[0] | e6[1];

        #pragma unroll
        for (int t = 0; t < 4; ++t) sh3[q][t][w] = e3[t];
        #pragma unroll
        for (int t = 0; t < 2; ++t) sh6[q][t][w] = e6[t];
        sh12[q][w] = e12;
        if (q == 1) sh4x[w] = e4[0];
    }
    __syncthreads();      // unconditional barrier

    if (tid < 512) {
        const int B = 32 * w;
        #pragma unroll
        for (int t = 0; t < 6; ++t) cs[0] += fold2cnt(e2[t]);
        #pragma unroll
        for (int t = 0; t < 3; ++t) cs[2] += fold4cnt(e4[t]);
        if (q == 0) {
            cs[4] += fold8cnt(e4[0] | e4[1]);
            cs[4] += fold8cnt(e4[2] | sh4x[w]);
        } else {
            cs[4] += fold8cnt(e4[1] | e4[2]);
        }
        #pragma unroll
        for (int gg = 0; gg < 4; ++gg) {
            unsigned int vn = (w < 255) ? sh3[q][gg][w + 1] : 0u;
            cs[1] += count_straddle<3, 3 * 2731>(e3[gg], vn, B);
        }
        #pragma unroll
        for (int gg = 0; gg < 2; ++gg) {
            if (rq / 6 + gg < 1365) {   // x-clamp: rows 8190-8191 dropped for k=6
                unsigned int vn = (w < 255) ? sh6[q][gg][w + 1] : 0u;
                cs[3] += count_straddle<6, 6 * 1365>(e6[gg], vn, B);
            }
        }
        if (rq / 12 < 683) {
            unsigned int vn = (w < 255) ? sh12[q][w + 1] : 0u;
            cs[5] += count_straddle<12, 12 * 683>(e12, vn, B);
        }
    }

    #pragma unroll
    for (int sI = 0; sI < NSIZES; ++sI) {
        int x = cs[sI];
        #pragma unroll
        for (int d = 32; d >= 1; d >>= 1) x += __shfl_xor(x, d);
        if (lane == 0 && x != 0) atomicAdd(&scnt[sI], x);   // LDS only
    }
    __syncthreads();
    if (tid < NSIZES) partials[g * NSIZES + tid] = scnt[tid];  // plain store
}

// finalize: reduce 342x6 partials + 512 blockmm, emit (3,6).
__global__ __launch_bounds__(256) void mpc13_finalize(
    const int* __restrict__ partials,
    const int2* __restrict__ blockmm,
    int nb,
    int* __restrict__ out)
{
    __shared__ int sacc[4][NSIZES];
    __shared__ int smin[4], smax[4];
    __shared__ int fcnt[NSIZES];
    __shared__ int fmin, fmax;

    int c[NSIZES] = {0, 0, 0, 0, 0, 0};
    for (int i = threadIdx.x; i < NSTRIPS; i += 256) {
        #pragma unroll
        for (int s = 0; s < NSIZES; ++s) c[s] += partials[i * NSIZES + s];
    }
    int a = INT_MAX, b = INT_MIN;
    for (int i = threadIdx.x; i < nb; i += 256) {
        int2 mm = blockmm[i];
        a = min(a, mm.x);
        b = max(b, mm.y);
    }
    #pragma unroll
    for (int d = 32; d >= 1; d >>= 1) {
        #pragma unroll
        for (int s = 0; s < NSIZES; ++s) c[s] += __shfl_xor(c[s], d);
        a = min(a, __shfl_xor(a, d));
        b = max(b, __shfl_xor(b, d));
    }
    const int wv = threadIdx.x >> 6;
    if ((threadIdx.x & 63) == 0) {
        #pragma unroll
        for (int s = 0; s < NSIZES; ++s) sacc[wv][s] = c[s];
        smin[wv] = a; smax[wv] = b;
    }
    __syncthreads();
    if (threadIdx.x == 0) {
        int x = smin[0], y = smax[0];
        #pragma unroll
        for (int t = 1; t < 4; ++t) { x = min(x, smin[t]); y = max(y, smax[t]); }
        fmin = x; fmax = y;
        #pragma unroll
        for (int s = 0; s < NSIZES; ++s)
            fcnt[s] = sacc[0][s] + sacc[1][s] + sacc[2][s] + sacc[3][s];
    }
    __syncthreads();
    const int t = threadIdx.x;
    if (t < NSIZES) {
        out[t] = fcnt[t];
        out[NSIZES + t] = fmin / d_K[t];       // umin >= 0
        out[2 * NSIZES + t] = fmax / d_K[t];   // includes OOB coords, as ref
    }
}

// ====================== Fallback shared kernels ============================
__global__ void mpc2_init(int* counters) {
    if (threadIdx.x == 0) { counters[6] = INT_MAX; counters[7] = INT_MIN; }
    if (threadIdx.x < NSIZES) counters[threadIdx.x] = 0;
}

__global__ void mpc2_finalize(const int* __restrict__ counters, int* __restrict__ out) {
    const int t = threadIdx.x;
    if (t < NSIZES) {
        out[t] = counters[t];
        out[NSIZES + t] = counters[6] / d_K[t];
        out[2 * NSIZES + t] = counters[7] / d_K[t];
    }
}

// Fallback B (R5): direct sliced bytemap scatter + bytemap count
__global__ __launch_bounds__(256) void mpc5_scatter(
    const f4v* __restrict__ pts4,
    const float2* __restrict__ pts,
    const float* __restrict__ psz,
    const float* __restrict__ pcmin,
    unsigned char* __restrict__ bm,
    int* __restrict__ counters,
    int npts)
{
    const float minx = pcmin[0];
    const float miny = pcmin[1];
    const float fine = psz[0] * 0.5f;

    const int bid = blockIdx.x;
    const unsigned int slice = (unsigned)((bid & 7) + ((bid >= NGROUPS * 8) ? 8 : 0));
    const int grp = (bid >> 3) & (NGROUPS - 1);
    const bool track = (slice == 0);

    const int nv = npts >> 1;
    const int cpg = (nv + NGROUPS - 1) / NGROUPS;
    const int i0 = grp * cpg;
    const int i1 = min(nv, i0 + cpg);

    int umin = INT_MAX, umax = INT_MIN;
    for (int i = i0 + (int)threadIdx.x; i < i1; i += 256) {
        f4v q = __builtin_nontemporal_load(pts4 + i);
        int ux0 = (int)floorf((q.x - minx) / fine);
        int uy0 = (int)floorf((q.y - miny) / fine);
        int ux1 = (int)floorf((q.z - minx) / fine);
        int uy1 = (int)floorf((q.w - miny) / fine);
        if (track) {
            umin = min(umin, min(ux0, ux1));
            umax = max(umax, max(ux0, ux1));
        }
        if (((unsigned)ux0 >> SLICE_SHIFT) == slice && (unsigned)uy0 < FINE)
            bm[(((size_t)(unsigned)ux0) << 13) + (unsigned)uy0] = 1;
        if (((unsigned)ux1 >> SLICE_SHIFT) == slice && (unsigned)uy1 < FINE)
            bm[(((size_t)(unsigned)ux1) << 13) + (unsigned)uy1] = 1;
    }
    if ((npts & 1) && grp == 0 && threadIdx.x == 0) {
        float2 p = pts[npts - 1];
        int ux = (int)floorf((p.x - minx) / fine);
        int uy = (int)floorf((p.y - miny) / fine);
        if (track) { umin = min(umin, ux); umax = max(umax, ux); }
        if (((unsigned)ux >> SLICE_SHIFT) == slice && (unsigned)uy < FINE)
            bm[(((size_t)(unsigned)ux) << 13) + (unsigned)uy] = 1;
    }
    if (track) {
        #pragma unroll
        for (int d = 32; d >= 1; d >>= 1) {
            umin = min(umin, __shfl_xor(umin, d));
            umax = max(umax, __shfl_xor(umax, d));
        }
        if ((threadIdx.x & 63) == 0) {
            atomicMin(&counters[6], umin);
            atomicMax(&counters[7], umax);
        }
    }
}

__global__ __launch_bounds__(512) void mpc4_count(
    const unsigned char* __restrict__ bm,
    int* __restrict__ counters)
{
    __shared__ unsigned int sh3[2][4][256];
    __shared__ unsigned int sh6[2][2][256];
    __shared__ unsigned int sh12[2][256];
    __shared__ unsigned int sh4x[256];
    __shared__ int scnt[NSIZES];

    const int w = threadIdx.x & 255;
    const int q = threadIdx.x >> 8;
    const int r0 = blockIdx.x * STRIP;
    const int rq = r0 + q * 12;

    if (threadIdx.x < NSIZES) scnt[threadIdx.x] = 0;

    unsigned int v[12];
    #pragma unroll
    for (int j = 0; j < 12; ++j) {
        unsigned int m = 0;
        const int row = rq + j;
        if (row < FINE) {
            const uint4* p = (const uint4*)(bm + (((size_t)row) << 13) + (w << 5));
            uint4 a = p[0], b = p[1];
            unsigned int ds[8] = {a.x, a.y, a.z, a.w, b.x, b.y, b.z, b.w};
            #pragma unroll
            for (int t = 0; t < 8; ++t) {
                unsigned int d = ds[t];
                d |= d >> 4; d |= d >> 2; d |= d >> 1;
                m |= (((d & 0x01010101u) * 0x01020408u) >> 24 & 0xFu) << (t * 4);
            }
        }
        v[j] = m;
    }

    unsigned int e2[6], e3[4], e4[3], e6[2], e12;
    #pragma unroll
    for (int t = 0; t < 6; ++t) e2[t] = v[2*t] | v[2*t+1];
    #pragma unroll
    for (int t = 0; t < 4; ++t) e3[t] = v[3*t] | v[3*t+1] | v[3*t+2];
    #pragma unroll
    for (int t = 0; t < 3; ++t) e4[t] = e2[2*t] | e2[2*t+1];
    #pragma unroll
    for (int t = 0; t < 2; ++t) e6[t] = e3[2*t] | e3[2*t+1];
    e12 = e6[0] | e6[1];

    #pragma unroll
    for (int t = 0; t < 4; ++t) sh3[q][t][w] = e3[t];
    #pragma unroll
    for (int t = 0; t < 2; ++t) sh6[q][t][w] = e6[t];
    sh12[q][w] = e12;
    if (q == 1) sh4x[w] = e4[0];
    __syncthreads();

    const int B = 32 * w;
    int c0 = 0, c1 = 0, c2 = 0, c3 = 0, c4 = 0, c5 = 0;

    #pragma unroll
    for (int t = 0; t < 6; ++t) c0 += fold2cnt(e2[t]);
    #pragma unroll
    for (int t = 0; t < 3; ++t) c2 += fold4cnt(e4[t]);
    if (q == 0) {
        c4 += fold8cnt(e4[0] | e4[1]);
        c4 += fold8cnt(e4[2] | sh4x[w]);
    } else {
        c4 += fold8cnt(e4[1] | e4[2]);
    }
    #pragma unroll
    for (int g = 0; g < 4; ++g) {
        unsigned int vn = (w < 255) ? sh3[q][g][w + 1] : 0u;
        c1 += count_straddle<3, 3 * 2731>(e3[g], vn, B);
    }
    #pragma unroll
    for (int g = 0; g < 2; ++g) {
        if (rq / 6 + g < 1365) {
            unsigned int vn = (w < 255) ? sh6[q][g][w + 1] : 0u;
            c3 += count_straddle<6, 6 * 1365>(e6[g], vn, B);
        }
    }
    if (rq / 12 < 683) {
        unsigned int vn = (w < 255) ? sh12[q][w + 1] : 0u;
        c5 += count_straddle<12, 12 * 683>(e12, vn, B);
    }

    int cs[NSIZES] = {c0, c1, c2, c3, c4, c5};
    #pragma unroll
    for (int s = 0; s < NSIZES; ++s) {
        int x = cs[s];
        #pragma unroll
        for (int d = 32; d >= 1; d >>= 1) x += __shfl_xor(x, d);
        if ((threadIdx.x & 63) == 0 && x != 0) atomicAdd(&scnt[s], x);
    }
    __syncthreads();
    if (threadIdx.x < NSIZES && scnt[threadIdx.x] != 0)
        atomicAdd(&counters[threadIdx.x], scnt[threadIdx.x]);
}

// Fallback C (R3): bitmap + atomics
__global__ __launch_bounds__(256) void mpc3_scatter(
    const float4* __restrict__ pts4,
    const float2* __restrict__ pts,
    const float* __restrict__ psz,
    const float* __restrict__ pcmin,
    unsigned int* __restrict__ bitmap,
    int* __restrict__ counters,
    int npts)
{
    const float minx = pcmin[0];
    const float miny = pcmin[1];
    const float fine = psz[0] * 0.5f;

    int umin = INT_MAX, umax = INT_MIN;
    const int nv = npts >> 1;
    const int stride = gridDim.x * blockDim.x;
    const int tid = blockIdx.x * blockDim.x + threadIdx.x;
    for (int i = tid; i < nv; i += stride) {
        float4 q = pts4[i];
        int ux0 = (int)floorf((q.x - minx) / fine);
        int uy0 = (int)floorf((q.y - miny) / fine);
        int ux1 = (int)floorf((q.z - minx) / fine);
        int uy1 = (int)floorf((q.w - miny) / fine);
        umin = min(umin, min(ux0, ux1));
        umax = max(umax, max(ux0, ux1));
        if ((unsigned)ux0 < FINE && (unsigned)uy0 < FINE)
            atomicOr(&bitmap[(unsigned)ux0 * WPR + ((unsigned)uy0 >> 5)], 1u << (uy0 & 31));
        if ((unsigned)ux1 < FINE && (unsigned)uy1 < FINE)
            atomicOr(&bitmap[(unsigned)ux1 * WPR + ((unsigned)uy1 >> 5)], 1u << (uy1 & 31));
    }
    if ((npts & 1) && tid == 0) {
        float2 p = pts[npts - 1];
        int ux = (int)floorf((p.x - minx) / fine);
        int uy = (int)floorf((p.y - miny) / fine);
        umin = min(umin, ux);
        umax = max(umax, ux);
        if ((unsigned)ux < FINE && (unsigned)uy < FINE)
            atomicOr(&bitmap[(unsigned)ux * WPR + ((unsigned)uy >> 5)], 1u << (uy & 31));
    }
    #pragma unroll
    for (int d = 32; d >= 1; d >>= 1) {
        umin = min(umin, __shfl_xor(umin, d));
        umax = max(umax, __shfl_xor(umax, d));
    }
    if ((threadIdx.x & 63) == 0) {
        atomicMin(&counters[6], umin);
        atomicMax(&counters[7], umax);
    }
}

__global__ __launch_bounds__(256) void mpc3_count(
    const unsigned int* __restrict__ bitmap,
    int* __restrict__ counters)
{
    __shared__ unsigned int sh[14][256];

    const int b = blockIdx.x;
    const int w = threadIdx.x;
    const int r0 = b * STRIP;
    const int nrows = min(STRIP, FINE - r0);

    unsigned int v[STRIP];
    #pragma unroll
    for (int j = 0; j < STRIP; ++j)
        v[j] = (j < nrows) ? bitmap[(size_t)(r0 + j) * WPR + w] : 0u;

    unsigned int g2[12], g3[8], g4[6], g6[4], g8[3], g12[2];
    #pragma unroll
    for (int j = 0; j < 12; ++j) g2[j] = v[2*j] | v[2*j+1];
    #pragma unroll
    for (int j = 0; j < 8;  ++j) g3[j] = v[3*j] | v[3*j+1] | v[3*j+2];
    #pragma unroll
    for (int j = 0; j < 6;  ++j) g4[j] = g2[2*j] | g2[2*j+1];
    #pragma unroll
    for (int j = 0; j < 4;  ++j) g6[j] = g3[2*j] | g3[2*j+1];
    #pragma unroll
    for (int j = 0; j < 3;  ++j) g8[j] = g4[2*j] | g4[2*j+1];
    #pragma unroll
    for (int j = 0; j < 2;  ++j) g12[j] = g6[2*j] | g6[2*j+1];

    #pragma unroll
    for (int j = 0; j < 8; ++j) sh[j][w] = g3[j];
    #pragma unroll
    for (int j = 0; j < 4; ++j) sh[8 + j][w] = g6[j];
    #pragma unroll
    for (int j = 0; j < 2; ++j) sh[12 + j][w] = g12[j];
    __syncthreads();

    int c0 = 0, c1 = 0, c2 = 0, c3 = 0, c4 = 0, c5 = 0;
    const int B = 32 * w;

    #pragma unroll
    for (int j = 0; j < 12; ++j) c0 += fold2cnt(g2[j]);
    #pragma unroll
    for (int j = 0; j < 6; ++j) c2 += fold4cnt(g4[j]);
    #pragma unroll
    for (int j = 0; j < 3; ++j) c4 += fold8cnt(g8[j]);
    #pragma unroll
    for (int j = 0; j < 8; ++j) {
        unsigned int vn = (w < 255) ? sh[j][w + 1] : 0u;
        c1 += count_straddle<3, 3 * 2731>(g3[j], vn, B);
    }
    #pragma unroll
    for (int j = 0; j < 4; ++j) {
        if (r0 / 6 + j < 1365) {
            unsigned int vn = (w < 255) ? sh[8 + j][w + 1] : 0u;
            c3 += count_straddle<6, 6 * 1365>(g6[j], vn, B);
        }
    }
    #pragma unroll
    for (int j = 0; j < 2; ++j) {
        unsigned int vn = (w < 255) ? sh[12 + j][w + 1] : 0u;
        c5 += count_straddle<12, 12 * 683>(g12[j], vn, B);
    }

    int cs[6] = {c0, c1, c2, c3, c4, c5};
    #pragma unroll
    for (int s = 0; s < 6; ++s) {
        int x = cs[s];
        #pragma unroll
        for (int d = 32; d >= 1; d >>= 1) x += __shfl_xor(x, d);
        if ((threadIdx.x & 63) == 0 && x != 0) atomicAdd(&counters[s], x);
    }
}

// ============================================================================
static inline size_t align256(size_t x) { return (x + 255) & ~(size_t)255; }

extern "C" void kernel_launch(void* const* d_in, const int* in_sizes, int n_in,
                              void* d_out, int out_size, void* d_ws, size_t ws_size,
                              hipStream_t stream) {
    const float2* pts  = (const float2*)d_in[0];
    const float* psz   = (const float*)d_in[1];
    const float* pcmin = (const float*)d_in[2];
    const int* gs      = (const int*)d_in[3];
    (void)gs;
    const int npts = in_sizes[0] / 2;

    // layout: ~23 MB
    const size_t bk_b = align256((size_t)NBLK * NBANDS * CAPB * sizeof(unsigned int));
    const size_t ct_b = align256((size_t)NBLK * NBANDS);
    const size_t mm_b = align256((size_t)NBLK * sizeof(int2));
    const size_t pt_b = align256((size_t)NSTRIPS * NSIZES * sizeof(int));
    const size_t new_need = bk_b + ct_b + mm_b + pt_b + 4096;

    const size_t byte_need = BYTEMAP_BYTES + 64;

    if (ws_size >= new_need) {
        char* p = (char*)d_ws;
        unsigned int* buckets = (unsigned int*)p;       p += bk_b;
        unsigned char* counts = (unsigned char*)p;      p += ct_b;
        int2* blockmm = (int2*)p;                       p += mm_b;
        int* partials = (int*)p;

        const int nv = npts >> 1;
        int vpb = (nv + NBLK - 1) / NBLK;
        vpb = (vpb + 1023) & ~1023;
        if (vpb < 1024) vpb = 1024;

        mpc17_part<<<NBLK, 512, 0, stream>>>((const f4v*)pts, pts, psz, pcmin,
                                             buckets, counts, blockmm, npts, vpb);
        mpc14_count<<<NSTRIPS, 1024, 0, stream>>>(buckets, counts, partials);
        mpc13_finalize<<<1, 256, 0, stream>>>(partials, blockmm, NBLK, (int*)d_out);
    } else if (ws_size >= byte_need) {
        unsigned char* bm = (unsigned char*)d_ws;
        int* counters = (int*)((char*)d_ws + BYTEMAP_BYTES);

        hipMemsetAsync(d_ws, 0, BYTEMAP_BYTES, stream);
        mpc2_init<<<1, 64, 0, stream>>>(counters);
        mpc5_scatter<<<NGROUPS * NSLICES, 256, 0, stream>>>(
            (const f4v*)pts, pts, psz, pcmin, bm, counters, npts);
        mpc4_count<<<NSTRIPS, 512, 0, stream>>>(bm, counters);
        mpc2_finalize<<<1, 64, 0, stream>>>(counters, (int*)d_out);
    } else {
        unsigned int* bitmap = (unsigned int*)d_ws;
        int* counters = (int*)d_ws + FINE_WORDS;

        hipMemsetAsync(d_ws, 0, (size_t)FINE_WORDS * sizeof(unsigned int), stream);
        mpc2_init<<<1, 64, 0, stream>>>(counters);
        mpc3_scatter<<<2048, 256, 0, stream>>>((const float4*)pts, pts, psz, pcmin,
                                               bitmap, counters, npts);
        mpc3_count<<<NSTRIPS, 256, 0, stream>>>(bitmap, counters);
        mpc2_finalize<<<1, 64, 0, stream>>>(counters, (int*)d_out);
    }
}